// Round 7
// baseline (153.224 us; speedup 1.0000x reference)
//
#include <hip/hip_runtime.h>
#include <hip/hip_bf16.h>

#define NSP 2304   // 48*48 spatial
#define NB  4      // batch

typedef unsigned short u16;
typedef __attribute__((ext_vector_type(8))) short short8;
typedef __attribute__((ext_vector_type(4))) float f32x4;
typedef __attribute__((ext_vector_type(4))) unsigned short u16x4;

// scale * log2(e), folded into Q at QKV-GEMM epilogue: softmax p = exp2(S)
#define K1S 0.25508040852656425f

static __device__ inline u16 f2bf(float f) {
  return __builtin_bit_cast(unsigned short, __float2bfloat16(f));
}

// ---------------------------------------------------------------------------
// prep 1: w_qkv (768*256) and w_out (256*256) fp32 -> bf16, one region.
// ---------------------------------------------------------------------------
__global__ __launch_bounds__(256) void convert_w(
    const float* __restrict__ wq, const float* __restrict__ wo,
    u16* __restrict__ dst) {
  int i = (blockIdx.x * 256 + threadIdx.x) * 4;
  float4 v;
  if (i < 196608) v = *(const float4*)(wq + i);
  else            v = *(const float4*)(wo + (i - 196608));
  u16x4 p = {f2bf(v.x), f2bf(v.y), f2bf(v.z), f2bf(v.w)};
  *(u16x4*)(dst + i) = p;
}

// ---------------------------------------------------------------------------
// prep 2: x fp32 [b][256][2304] -> xT bf16 [b][2304][256]
// ---------------------------------------------------------------------------
__global__ __launch_bounds__(256) void transpose_x(
    const float* __restrict__ x, u16* __restrict__ xT) {
  __shared__ float tile[32][33];
  const int t = threadIdx.x;
  const int n0 = blockIdx.x * 32, c0 = blockIdx.y * 32, b = blockIdx.z;
  const float* xb = x + ((size_t)b * 256 + c0) * NSP + n0;
#pragma unroll
  for (int e = t; e < 1024; e += 256) {
    int cc = e >> 5, nn = e & 31;
    tile[cc][nn] = xb[(size_t)cc * NSP + nn];
  }
  __syncthreads();
  u16* xTb = xT + ((size_t)b * NSP + n0) * 256 + c0;
#pragma unroll
  for (int e = t; e < 1024; e += 256) {
    int nn = e >> 5, cc = e & 31;
    xTb[(size_t)nn * 256 + cc] = f2bf(tile[cc][nn]);
  }
}

// ---------------------------------------------------------------------------
// bf16 MFMA GEMM (LDS-staged): D = A (Mx256) * B[b](Nx256)^T
// 64x64 tile, 4 waves (2x2 of 32x32), whole K=256 staged once.
// EPI 0: rows <256 q (pre-scaled K1S), 256..511 k -> qkT[b][n][512] bf16;
//        rows >=512 v -> vbuf[b][256][2304] bf16.
// EPI 1: fp32 out + bias.
// ---------------------------------------------------------------------------
template <int EPI>
__global__ __launch_bounds__(256) void gemm_mfma(
    const u16* __restrict__ A, const u16* __restrict__ B,
    u16* __restrict__ qkT, u16* __restrict__ vbuf,
    float* __restrict__ outf, const float* __restrict__ bias, int N) {
  __shared__ u16 As[64][264];
  __shared__ u16 Bs[64][264];
  const int t = threadIdx.x, lane = t & 63, wid = t >> 6;
  const int lo = lane & 15, g = lane >> 4;
  const int wr = wid >> 1, wc = wid & 1;
  const int row0 = blockIdx.y * 64, col0 = blockIdx.x * 64, b = blockIdx.z;

  const int sr = t >> 2, c4 = t & 3;
  const u16* Arow = A + (size_t)(row0 + sr) * 256;
  const u16* Brow = B + ((size_t)b * N + col0 + sr) * 256;
#pragma unroll
  for (int i = 0; i < 8; ++i) {
    int col = (c4 + 4 * i) * 8;
    *(uint4*)&As[sr][col] = *(const uint4*)&Arow[col];
    *(uint4*)&Bs[sr][col] = *(const uint4*)&Brow[col];
  }
  __syncthreads();

  f32x4 acc[2][2];
#pragma unroll
  for (int i = 0; i < 2; ++i)
#pragma unroll
    for (int j = 0; j < 2; ++j) acc[i][j] = (f32x4){0, 0, 0, 0};

  const int ar0 = wr * 32 + lo, br0 = wc * 32 + lo;
#pragma unroll
  for (int kk = 0; kk < 8; ++kk) {
    int kc = kk * 32 + g * 8;
    short8 a0 = *(const short8*)&As[ar0][kc];
    short8 a1 = *(const short8*)&As[ar0 + 16][kc];
    short8 b0 = *(const short8*)&Bs[br0][kc];
    short8 b1 = *(const short8*)&Bs[br0 + 16][kc];
    acc[0][0] = __builtin_amdgcn_mfma_f32_16x16x32_bf16(a0, b0, acc[0][0], 0, 0, 0);
    acc[0][1] = __builtin_amdgcn_mfma_f32_16x16x32_bf16(a0, b1, acc[0][1], 0, 0, 0);
    acc[1][0] = __builtin_amdgcn_mfma_f32_16x16x32_bf16(a1, b0, acc[1][0], 0, 0, 0);
    acc[1][1] = __builtin_amdgcn_mfma_f32_16x16x32_bf16(a1, b1, acc[1][1], 0, 0, 0);
  }

  const float qs = (EPI == 0 && row0 < 256) ? K1S : 1.0f;
#pragma unroll
  for (int m2 = 0; m2 < 2; ++m2)
#pragma unroll
    for (int n2 = 0; n2 < 2; ++n2) {
      int m = row0 + wr * 32 + m2 * 16 + g * 4;
      int n = col0 + wc * 32 + n2 * 16 + lo;
      if constexpr (EPI == 0) {
        if (row0 < 512) {  // q,k -> transposed qkT[b][n][m..m+3]
          u16x4 pk = {f2bf(acc[m2][n2][0] * qs), f2bf(acc[m2][n2][1] * qs),
                      f2bf(acc[m2][n2][2] * qs), f2bf(acc[m2][n2][3] * qs)};
          *(u16x4*)(qkT + ((size_t)b * NSP + n) * 512 + m) = pk;
        } else {           // v -> natural vbuf[b][m-512][n]
#pragma unroll
          for (int r = 0; r < 4; ++r)
            vbuf[((size_t)b * 256 + (m - 512 + r)) * NSP + n] =
                f2bf(acc[m2][n2][r]);
        }
      } else {
#pragma unroll
        for (int r = 0; r < 4; ++r)
          outf[((size_t)b * 256 + m + r) * NSP + n] =
              acc[m2][n2][r] + bias[m + r];
      }
    }
}

// ---------------------------------------------------------------------------
// MFMA flash attention, KEY-SPLIT 8-wave blocks (512 thr).
// Wave w: query subtile wq = w&3 (16 q), key half par = w>>2.
// Period = 128 keys staged once (single-buffered, 2 barriers); parity p
// computes the 64-key window [par*64, par*64+64) of each period. 18 periods.
// Softmax: p = exp2(S) (scale folded into Q upstream, no max tracking);
// SWAPPED S = mfma(K,Q) so each lane holds P for a fixed query -> packed
// b64 Ps writes. Row-sum l via ones-MFMA. Parity merge = plain add at end.
// ---------------------------------------------------------------------------
__global__ __launch_bounds__(512, 8) void attn_mfma(
    const u16* __restrict__ qkT, const u16* __restrict__ vbuf,
    u16* __restrict__ attnoT) {
  const int it = blockIdx.x, h = blockIdx.y, b = blockIdx.z;
  const int t = threadIdx.x, lane = t & 63, w = t >> 6;
  const int wq = w & 3, par = w >> 2;
  const int lo = lane & 15, g = lane >> 4;
  const int i0 = it * 64;

  const u16* qkTb = qkT + (size_t)b * NSP * 512;
  const u16* vb   = vbuf + ((size_t)b * 256 + h * 32) * NSP;
  u16* ob = attnoT + ((size_t)b * NSP + i0) * 256 + h * 32;

  __shared__ union SU {
    struct { u16 Kt[128][40]; u16 Vs[32][136]; } s;  // 18944 B
    float mrg[4][64][12];                            // 12288 B (epilogue reuse)
  } u;
  __shared__ u16 Ps[8][16][72];                      // per-wave P, 18432 B

  // Q fragment (pre-scaled by K1S upstream)
  short8 qf = *(const short8*)(qkTb + (size_t)(i0 + wq * 16 + lo) * 512 +
                               h * 32 + g * 8);

  // staging: one b128 per thread per buffer per period (512 thr)
  const int kr = t >> 2, kp = (t & 3) * 8;    // K: row j (128), d-part
  const int vr = t >> 4, vp = (t & 15) * 8;   // V: row d (32), j-part
  const u16* ksrc = qkTb + 256 + h * 32 + kp;            // + j*512
  const u16* vsrc = vb + (size_t)vr * NSP + vp;          // + j0

  uint4 kreg = *(const uint4*)(ksrc + (size_t)kr * 512);
  uint4 vreg = *(const uint4*)(vsrc);
  *(uint4*)&u.s.Kt[kr][kp] = kreg;
  *(uint4*)&u.s.Vs[vr][vp] = vreg;
  __syncthreads();

  short8 ones;
#pragma unroll
  for (int e = 0; e < 8; ++e) ones[e] = (short)0x3F80;  // bf16 1.0

  f32x4 acc0 = {0, 0, 0, 0}, acc1 = {0, 0, 0, 0}, accl = {0, 0, 0, 0};
  const int poff = par * 64;

  for (int tp = 0; tp < 18; ++tp) {
    if (tp + 1 < 18) {  // prefetch next period into regs
      int j0n = (tp + 1) * 128;
      kreg = *(const uint4*)(ksrc + (size_t)(j0n + kr) * 512);
      vreg = *(const uint4*)(vsrc + j0n);
    }

    // ---- S^T = mfma(K, Q): lane holds S[q=lo][j=poff+jt*16+g*4+r] ----
    f32x4 sv[4];
#pragma unroll
    for (int jt = 0; jt < 4; ++jt) {
      short8 kf = *(const short8*)&u.s.Kt[poff + jt * 16 + lo][g * 8];
      sv[jt] = __builtin_amdgcn_mfma_f32_16x16x32_bf16(
          kf, qf, (f32x4){0, 0, 0, 0}, 0, 0, 0);
    }

    // ---- p = exp2(S), packed b64 writes (4 per strip) ----
#pragma unroll
    for (int jt = 0; jt < 4; ++jt) {
      u16x4 pk = {f2bf(__builtin_amdgcn_exp2f(sv[jt][0])),
                  f2bf(__builtin_amdgcn_exp2f(sv[jt][1])),
                  f2bf(__builtin_amdgcn_exp2f(sv[jt][2])),
                  f2bf(__builtin_amdgcn_exp2f(sv[jt][3]))};
      *(u16x4*)&Ps[w][lo][jt * 16 + g * 4] = pk;
    }

    // ---- PV + row-sum l (all MFMA) ----
    short8 pf0  = *(const short8*)&Ps[w][lo][g * 8];
    short8 pf1  = *(const short8*)&Ps[w][lo][32 + g * 8];
    short8 vf00 = *(const short8*)&u.s.Vs[lo][poff + g * 8];
    short8 vf01 = *(const short8*)&u.s.Vs[lo][poff + 32 + g * 8];
    short8 vf10 = *(const short8*)&u.s.Vs[16 + lo][poff + g * 8];
    short8 vf11 = *(const short8*)&u.s.Vs[16 + lo][poff + 32 + g * 8];
    acc0 = __builtin_amdgcn_mfma_f32_16x16x32_bf16(pf0, vf00, acc0, 0, 0, 0);
    acc1 = __builtin_amdgcn_mfma_f32_16x16x32_bf16(pf0, vf10, acc1, 0, 0, 0);
    accl = __builtin_amdgcn_mfma_f32_16x16x32_bf16(pf0, ones, accl, 0, 0, 0);
    acc0 = __builtin_amdgcn_mfma_f32_16x16x32_bf16(pf1, vf01, acc0, 0, 0, 0);
    acc1 = __builtin_amdgcn_mfma_f32_16x16x32_bf16(pf1, vf11, acc1, 0, 0, 0);
    accl = __builtin_amdgcn_mfma_f32_16x16x32_bf16(pf1, ones, accl, 0, 0, 0);

    __syncthreads();               // all reads of this period done
    if (tp + 1 < 18) {
      *(uint4*)&u.s.Kt[kr][kp] = kreg;
      *(uint4*)&u.s.Vs[vr][vp] = vreg;
      __syncthreads();             // next period visible
    }
  }

  // ---- parity merge (accumulators simply add: shared exp2 offset) ----
  if (par == 1) {
    *(f32x4*)&u.mrg[wq][lane][0] = acc0;
    *(f32x4*)&u.mrg[wq][lane][4] = acc1;
    *(f32x4*)&u.mrg[wq][lane][8] = accl;
  }
  __syncthreads();
  if (par == 0) {
    f32x4 m0 = *(const f32x4*)&u.mrg[wq][lane][0];
    f32x4 m1 = *(const f32x4*)&u.mrg[wq][lane][4];
    f32x4 ml = *(const f32x4*)&u.mrg[wq][lane][8];
#pragma unroll
    for (int r = 0; r < 4; ++r) {
      float inv = 1.0f / (accl[r] + ml[r]);
      int row = wq * 16 + g * 4 + r;
      ob[(size_t)row * 256 + lo]      = f2bf((acc0[r] + m0[r]) * inv);
      ob[(size_t)row * 256 + 16 + lo] = f2bf((acc1[r] + m1[r]) * inv);
    }
  }
}

// ---------------------------------------------------------------------------
extern "C" void kernel_launch(void* const* d_in, const int* in_sizes, int n_in,
                              void* d_out, int out_size, void* d_ws, size_t ws_size,
                              hipStream_t stream) {
  const float* x     = (const float*)d_in[0];  // [4][256][48][48]
  const float* w_qkv = (const float*)d_in[1];  // [768][256]
  const float* w_out = (const float*)d_in[2];  // [256][256]
  const float* b_out = (const float*)d_in[3];  // [256]
  float* out = (float*)d_out;                  // [4][256][2304]

  u16* wbf    = (u16*)d_ws;                    // wqkv 196608 then wout 65536
  u16* xT     = wbf + 262144;                  // [4][2304][256]
  u16* qkT    = xT + (size_t)NB * NSP * 256;   // [4][2304][512]
  u16* vbuf   = qkT + (size_t)NB * NSP * 512;  // [4][256][2304]
  u16* attnoT = vbuf + (size_t)NB * 256 * NSP; // [4][2304][256]

  dim3 blk(256);
  convert_w<<<256, blk, 0, stream>>>(w_qkv, w_out, wbf);
  transpose_x<<<dim3(NSP / 32, 8, NB), blk, 0, stream>>>(x, xT);
  gemm_mfma<0><<<dim3(NSP / 64, 12, NB), blk, 0, stream>>>(
      wbf, xT, qkT, vbuf, nullptr, nullptr, NSP);
  attn_mfma<<<dim3(NSP / 64, 8, NB), dim3(512), 0, stream>>>(qkT, vbuf, attnoT);
  gemm_mfma<1><<<dim3(NSP / 64, 4, NB), blk, 0, stream>>>(
      wbf + 196608, attnoT, nullptr, nullptr, out, b_out, NSP);
}

// Round 8
// 81.507 us; speedup vs baseline: 1.8799x; 1.8799x over previous
//
#include <hip/hip_runtime.h>
#include <hip/hip_bf16.h>

#define NSP 2304   // 48*48 spatial
#define NB  4      // batch

typedef unsigned short u16;
typedef __attribute__((ext_vector_type(8))) short short8;
typedef __attribute__((ext_vector_type(4))) short short4v;
typedef __attribute__((ext_vector_type(4))) float f32x4;
typedef __attribute__((ext_vector_type(4))) unsigned short u16x4;

// scale * log2(e), folded into Q at QKV-GEMM epilogue: softmax p = exp2(S)
#define K1S 0.25508040852656425f

static __device__ inline u16 f2bf(float f) {
  return __builtin_bit_cast(unsigned short, __float2bfloat16(f));
}

// ---------------------------------------------------------------------------
// prep 1: w_qkv (768*256) and w_out (256*256) fp32 -> bf16, one region.
// ---------------------------------------------------------------------------
__global__ __launch_bounds__(256) void convert_w(
    const float* __restrict__ wq, const float* __restrict__ wo,
    u16* __restrict__ dst) {
  int i = (blockIdx.x * 256 + threadIdx.x) * 4;
  float4 v;
  if (i < 196608) v = *(const float4*)(wq + i);
  else            v = *(const float4*)(wo + (i - 196608));
  u16x4 p = {f2bf(v.x), f2bf(v.y), f2bf(v.z), f2bf(v.w)};
  *(u16x4*)(dst + i) = p;
}

// ---------------------------------------------------------------------------
// prep 2: x fp32 [b][256][2304] -> xT bf16 [b][2304][256]
// ---------------------------------------------------------------------------
__global__ __launch_bounds__(256) void transpose_x(
    const float* __restrict__ x, u16* __restrict__ xT) {
  __shared__ float tile[32][33];
  const int t = threadIdx.x;
  const int n0 = blockIdx.x * 32, c0 = blockIdx.y * 32, b = blockIdx.z;
  const float* xb = x + ((size_t)b * 256 + c0) * NSP + n0;
#pragma unroll
  for (int e = t; e < 1024; e += 256) {
    int cc = e >> 5, nn = e & 31;
    tile[cc][nn] = xb[(size_t)cc * NSP + nn];
  }
  __syncthreads();
  u16* xTb = xT + ((size_t)b * NSP + n0) * 256 + c0;
#pragma unroll
  for (int e = t; e < 1024; e += 256) {
    int nn = e >> 5, cc = e & 31;
    xTb[(size_t)nn * 256 + cc] = f2bf(tile[cc][nn]);
  }
}

// ---------------------------------------------------------------------------
// bf16 MFMA GEMM (LDS-staged): D = A (Mx256) * B[b](Nx256)^T
// 64x64 tile, 4 waves (2x2 of 32x32), whole K=256 staged once.
// EPI 0: rows <256 q (pre-scaled K1S), 256..511 k -> qkT[b][n][512] bf16;
//        rows >=512 v -> vbuf[b][256][2304] bf16.
// EPI 1: fp32 out + bias.
// ---------------------------------------------------------------------------
template <int EPI>
__global__ __launch_bounds__(256) void gemm_mfma(
    const u16* __restrict__ A, const u16* __restrict__ B,
    u16* __restrict__ qkT, u16* __restrict__ vbuf,
    float* __restrict__ outf, const float* __restrict__ bias, int N) {
  __shared__ u16 As[64][264];
  __shared__ u16 Bs[64][264];
  const int t = threadIdx.x, lane = t & 63, wid = t >> 6;
  const int lo = lane & 15, g = lane >> 4;
  const int wr = wid >> 1, wc = wid & 1;
  const int row0 = blockIdx.y * 64, col0 = blockIdx.x * 64, b = blockIdx.z;

  const int sr = t >> 2, c4 = t & 3;
  const u16* Arow = A + (size_t)(row0 + sr) * 256;
  const u16* Brow = B + ((size_t)b * N + col0 + sr) * 256;
#pragma unroll
  for (int i = 0; i < 8; ++i) {
    int col = (c4 + 4 * i) * 8;
    *(uint4*)&As[sr][col] = *(const uint4*)&Arow[col];
    *(uint4*)&Bs[sr][col] = *(const uint4*)&Brow[col];
  }
  __syncthreads();

  f32x4 acc[2][2];
#pragma unroll
  for (int i = 0; i < 2; ++i)
#pragma unroll
    for (int j = 0; j < 2; ++j) acc[i][j] = (f32x4){0, 0, 0, 0};

  const int ar0 = wr * 32 + lo, br0 = wc * 32 + lo;
#pragma unroll
  for (int kk = 0; kk < 8; ++kk) {
    int kc = kk * 32 + g * 8;
    short8 a0 = *(const short8*)&As[ar0][kc];
    short8 a1 = *(const short8*)&As[ar0 + 16][kc];
    short8 b0 = *(const short8*)&Bs[br0][kc];
    short8 b1 = *(const short8*)&Bs[br0 + 16][kc];
    acc[0][0] = __builtin_amdgcn_mfma_f32_16x16x32_bf16(a0, b0, acc[0][0], 0, 0, 0);
    acc[0][1] = __builtin_amdgcn_mfma_f32_16x16x32_bf16(a0, b1, acc[0][1], 0, 0, 0);
    acc[1][0] = __builtin_amdgcn_mfma_f32_16x16x32_bf16(a1, b0, acc[1][0], 0, 0, 0);
    acc[1][1] = __builtin_amdgcn_mfma_f32_16x16x32_bf16(a1, b1, acc[1][1], 0, 0, 0);
  }

  const float qs = (EPI == 0 && row0 < 256) ? K1S : 1.0f;
#pragma unroll
  for (int m2 = 0; m2 < 2; ++m2)
#pragma unroll
    for (int n2 = 0; n2 < 2; ++n2) {
      int m = row0 + wr * 32 + m2 * 16 + g * 4;
      int n = col0 + wc * 32 + n2 * 16 + lo;
      if constexpr (EPI == 0) {
        if (row0 < 512) {  // q,k -> transposed qkT[b][n][m..m+3]
          u16x4 pk = {f2bf(acc[m2][n2][0] * qs), f2bf(acc[m2][n2][1] * qs),
                      f2bf(acc[m2][n2][2] * qs), f2bf(acc[m2][n2][3] * qs)};
          *(u16x4*)(qkT + ((size_t)b * NSP + n) * 512 + m) = pk;
        } else {           // v -> natural vbuf[b][m-512][n]
#pragma unroll
          for (int r = 0; r < 4; ++r)
            vbuf[((size_t)b * 256 + (m - 512 + r)) * NSP + n] =
                f2bf(acc[m2][n2][r]);
        }
      } else {
#pragma unroll
        for (int r = 0; r < 4; ++r)
          outf[((size_t)b * 256 + m + r) * NSP + n] =
              acc[m2][n2][r] + bias[m + r];
      }
    }
}

// ---------------------------------------------------------------------------
// MFMA flash attention, P NEVER TOUCHES LDS.
// r6 pipeline (reg-prefetch -> double-buffered LDS K/V, 1 barrier/strip);
// SWAPPED S^T = mfma(K,Q): lane holds S[j=16jt+4g+r][q=lo] (HW-verified r7).
// k-permutation trick: PV uses sigma(g,e) = 16*(e>>2) + 4g + (e&3) as the
// position->key map on BOTH operands (positional contraction => any shared
// bijection is valid), so pf registers are exactly the exp2 outputs in order
// and V is read as b64 pairs under the same sigma. Row-sum l via ones-MFMA.
// ---------------------------------------------------------------------------
__global__ __launch_bounds__(256) void attn_mfma(
    const u16* __restrict__ qkT, const u16* __restrict__ vbuf,
    u16* __restrict__ attnoT) {
  const int it = blockIdx.x, h = blockIdx.y, b = blockIdx.z;
  const int t = threadIdx.x, lane = t & 63, wq = t >> 6;
  const int lo = lane & 15, g = lane >> 4;
  const int i0 = it * 64;

  const u16* qkTb = qkT + (size_t)b * NSP * 512;
  const u16* vb   = vbuf + ((size_t)b * 256 + h * 32) * NSP;
  u16* ob = attnoT + ((size_t)b * NSP + i0) * 256 + h * 32;

  __shared__ u16 Kt[2][64][40];   // [j][d]
  __shared__ u16 Vs[2][32][72];   // [d][j]

  // Q fragment (pre-scaled by K1S upstream); B-operand of swapped QK^T
  short8 qf = *(const short8*)(qkTb + (size_t)(i0 + wq * 16 + lo) * 512 +
                               h * 32 + g * 8);

  // staging addresses (one b128 per thread per buffer)
  const int kr = t >> 2, kp = (t & 3) * 8;   // K: row j (64), d-part
  const int vr = t >> 3, vp = (t & 7) * 8;   // V: row d (32), j-part
  const u16* ksrc = qkTb + 256 + h * 32 + kp;           // + j*512
  const u16* vsrc = vb + (size_t)vr * NSP + vp;         // + j0

  uint4 kreg = *(const uint4*)(ksrc + (size_t)kr * 512);
  uint4 vreg = *(const uint4*)(vsrc);
  *(uint4*)&Kt[0][kr][kp] = kreg;
  *(uint4*)&Vs[0][vr][vp] = vreg;
  __syncthreads();

  short8 ones;
#pragma unroll
  for (int e = 0; e < 8; ++e) ones[e] = (short)0x3F80;  // bf16 1.0

  f32x4 acc0 = {0, 0, 0, 0}, acc1 = {0, 0, 0, 0}, accl = {0, 0, 0, 0};

  for (int s = 0; s < 36; ++s) {
    const int cur = s & 1;
    if (s + 1 < 36) {  // prefetch next strip into regs
      int j0n = (s + 1) * 64;
      kreg = *(const uint4*)(ksrc + (size_t)(j0n + kr) * 512);
      vreg = *(const uint4*)(vsrc + j0n);
    }

    // ---- S^T = mfma(K, Q): lane holds S[j=16jt+4g+r][q=lo] ----
    f32x4 sv[4];
#pragma unroll
    for (int jt = 0; jt < 4; ++jt) {
      short8 kf = *(const short8*)&Kt[cur][jt * 16 + lo][g * 8];
      sv[jt] = __builtin_amdgcn_mfma_f32_16x16x32_bf16(
          kf, qf, (f32x4){0, 0, 0, 0}, 0, 0, 0);
    }

    // ---- p = exp2(S), packed in-register under sigma (no LDS!) ----
    short8 pf0, pf1;
#pragma unroll
    for (int e = 0; e < 8; ++e) {
      pf0[e] = (short)f2bf(__builtin_amdgcn_exp2f(sv[e >> 2][e & 3]));
      pf1[e] = (short)f2bf(__builtin_amdgcn_exp2f(sv[2 + (e >> 2)][e & 3]));
    }

    // ---- V fragments under sigma: b64 pairs at j = {4g, 16+4g} (+32) ----
    short4v v00a = *(const short4v*)&Vs[cur][lo][4 * g];
    short4v v00b = *(const short4v*)&Vs[cur][lo][16 + 4 * g];
    short4v v01a = *(const short4v*)&Vs[cur][lo][32 + 4 * g];
    short4v v01b = *(const short4v*)&Vs[cur][lo][48 + 4 * g];
    short4v v10a = *(const short4v*)&Vs[cur][16 + lo][4 * g];
    short4v v10b = *(const short4v*)&Vs[cur][16 + lo][16 + 4 * g];
    short4v v11a = *(const short4v*)&Vs[cur][16 + lo][32 + 4 * g];
    short4v v11b = *(const short4v*)&Vs[cur][16 + lo][48 + 4 * g];
    short8 vf00 = __builtin_shufflevector(v00a, v00b, 0, 1, 2, 3, 4, 5, 6, 7);
    short8 vf01 = __builtin_shufflevector(v01a, v01b, 0, 1, 2, 3, 4, 5, 6, 7);
    short8 vf10 = __builtin_shufflevector(v10a, v10b, 0, 1, 2, 3, 4, 5, 6, 7);
    short8 vf11 = __builtin_shufflevector(v11a, v11b, 0, 1, 2, 3, 4, 5, 6, 7);

    // ---- PV + row-sum l (all MFMA) ----
    acc0 = __builtin_amdgcn_mfma_f32_16x16x32_bf16(pf0, vf00, acc0, 0, 0, 0);
    acc1 = __builtin_amdgcn_mfma_f32_16x16x32_bf16(pf0, vf10, acc1, 0, 0, 0);
    accl = __builtin_amdgcn_mfma_f32_16x16x32_bf16(pf0, ones, accl, 0, 0, 0);
    acc0 = __builtin_amdgcn_mfma_f32_16x16x32_bf16(pf1, vf01, acc0, 0, 0, 0);
    acc1 = __builtin_amdgcn_mfma_f32_16x16x32_bf16(pf1, vf11, acc1, 0, 0, 0);
    accl = __builtin_amdgcn_mfma_f32_16x16x32_bf16(pf1, ones, accl, 0, 0, 0);

    if (s + 1 < 36) {  // write next strip into the other buffer
      *(uint4*)&Kt[cur ^ 1][kr][kp] = kreg;
      *(uint4*)&Vs[cur ^ 1][vr][vp] = vreg;
    }
    __syncthreads();
  }

  // ---- normalize + bf16 store to attnoT[n][c] ----
#pragma unroll
  for (int r = 0; r < 4; ++r) {
    float inv = 1.0f / accl[r];
    int row = wq * 16 + g * 4 + r;
    ob[(size_t)row * 256 + lo]      = f2bf(acc0[r] * inv);
    ob[(size_t)row * 256 + 16 + lo] = f2bf(acc1[r] * inv);
  }
}

// ---------------------------------------------------------------------------
extern "C" void kernel_launch(void* const* d_in, const int* in_sizes, int n_in,
                              void* d_out, int out_size, void* d_ws, size_t ws_size,
                              hipStream_t stream) {
  const float* x     = (const float*)d_in[0];  // [4][256][48][48]
  const float* w_qkv = (const float*)d_in[1];  // [768][256]
  const float* w_out = (const float*)d_in[2];  // [256][256]
  const float* b_out = (const float*)d_in[3];  // [256]
  float* out = (float*)d_out;                  // [4][256][2304]

  u16* wbf    = (u16*)d_ws;                    // wqkv 196608 then wout 65536
  u16* xT     = wbf + 262144;                  // [4][2304][256]
  u16* qkT    = xT + (size_t)NB * NSP * 256;   // [4][2304][512]
  u16* vbuf   = qkT + (size_t)NB * NSP * 512;  // [4][256][2304]
  u16* attnoT = vbuf + (size_t)NB * 256 * NSP; // [4][2304][256]

  dim3 blk(256);
  convert_w<<<256, blk, 0, stream>>>(w_qkv, w_out, wbf);
  transpose_x<<<dim3(NSP / 32, 8, NB), blk, 0, stream>>>(x, xT);
  gemm_mfma<0><<<dim3(NSP / 64, 12, NB), blk, 0, stream>>>(
      wbf, xT, qkT, vbuf, nullptr, nullptr, NSP);
  attn_mfma<<<dim3(NSP / 64, 8, NB), blk, 0, stream>>>(qkT, vbuf, attnoT);
  gemm_mfma<1><<<dim3(NSP / 64, 4, NB), blk, 0, stream>>>(
      wbf + 196608, attnoT, nullptr, nullptr, out, b_out, NSP);
}

// Round 9
// 81.501 us; speedup vs baseline: 1.8800x; 1.0001x over previous
//
#include <hip/hip_runtime.h>
#include <hip/hip_bf16.h>

#define NSP 2304   // 48*48 spatial
#define NB  4      // batch

typedef unsigned short u16;
typedef __attribute__((ext_vector_type(8))) short short8;
typedef __attribute__((ext_vector_type(4))) short short4v;
typedef __attribute__((ext_vector_type(4))) float f32x4;
typedef __attribute__((ext_vector_type(4))) unsigned short u16x4;

// scale * log2(e), folded into Q at QKV-GEMM epilogue: softmax p = exp2(S)
#define K1S 0.25508040852656425f

static __device__ inline u16 f2bf(float f) {
  return __builtin_bit_cast(unsigned short, __float2bfloat16(f));
}
// packed f32x2 -> bf16x2 (RNE), single VALU inst; lo16 = cvt(a), hi16 = cvt(b)
static __device__ inline unsigned cvtpk(float a, float b) {
  unsigned r;
  asm("v_cvt_pk_bf16_f32 %0, %1, %2" : "=v"(r) : "v"(a), "v"(b));
  return r;
}

// ---------------------------------------------------------------------------
// prep 1: w_qkv (768*256) and w_out (256*256) fp32 -> bf16, one region.
// ---------------------------------------------------------------------------
__global__ __launch_bounds__(256) void convert_w(
    const float* __restrict__ wq, const float* __restrict__ wo,
    u16* __restrict__ dst) {
  int i = (blockIdx.x * 256 + threadIdx.x) * 4;
  float4 v;
  if (i < 196608) v = *(const float4*)(wq + i);
  else            v = *(const float4*)(wo + (i - 196608));
  u16x4 p = {f2bf(v.x), f2bf(v.y), f2bf(v.z), f2bf(v.w)};
  *(u16x4*)(dst + i) = p;
}

// ---------------------------------------------------------------------------
// prep 2: x fp32 [b][256][2304] -> xT bf16 [b][2304][256]
// ---------------------------------------------------------------------------
__global__ __launch_bounds__(256) void transpose_x(
    const float* __restrict__ x, u16* __restrict__ xT) {
  __shared__ float tile[32][33];
  const int t = threadIdx.x;
  const int n0 = blockIdx.x * 32, c0 = blockIdx.y * 32, b = blockIdx.z;
  const float* xb = x + ((size_t)b * 256 + c0) * NSP + n0;
#pragma unroll
  for (int e = t; e < 1024; e += 256) {
    int cc = e >> 5, nn = e & 31;
    tile[cc][nn] = xb[(size_t)cc * NSP + nn];
  }
  __syncthreads();
  u16* xTb = xT + ((size_t)b * NSP + n0) * 256 + c0;
#pragma unroll
  for (int e = t; e < 1024; e += 256) {
    int nn = e >> 5, cc = e & 31;
    xTb[(size_t)nn * 256 + cc] = f2bf(tile[cc][nn]);
  }
}

// ---------------------------------------------------------------------------
// bf16 MFMA GEMM (LDS-staged): D = A (Mx256) * B[b](Nx256)^T
// 64x64 tile, 4 waves (2x2 of 32x32), whole K=256 staged once.
// EPI 0: rows <256 q (pre-scaled K1S), 256..511 k -> qkT[b][n][512] bf16;
//        rows >=512 v -> vbuf[b][256][2304] bf16.
// EPI 1: fp32 out + bias.
// ---------------------------------------------------------------------------
template <int EPI>
__global__ __launch_bounds__(256) void gemm_mfma(
    const u16* __restrict__ A, const u16* __restrict__ B,
    u16* __restrict__ qkT, u16* __restrict__ vbuf,
    float* __restrict__ outf, const float* __restrict__ bias, int N) {
  __shared__ u16 As[64][264];
  __shared__ u16 Bs[64][264];
  const int t = threadIdx.x, lane = t & 63, wid = t >> 6;
  const int lo = lane & 15, g = lane >> 4;
  const int wr = wid >> 1, wc = wid & 1;
  const int row0 = blockIdx.y * 64, col0 = blockIdx.x * 64, b = blockIdx.z;

  const int sr = t >> 2, c4 = t & 3;
  const u16* Arow = A + (size_t)(row0 + sr) * 256;
  const u16* Brow = B + ((size_t)b * N + col0 + sr) * 256;
#pragma unroll
  for (int i = 0; i < 8; ++i) {
    int col = (c4 + 4 * i) * 8;
    *(uint4*)&As[sr][col] = *(const uint4*)&Arow[col];
    *(uint4*)&Bs[sr][col] = *(const uint4*)&Brow[col];
  }
  __syncthreads();

  f32x4 acc[2][2];
#pragma unroll
  for (int i = 0; i < 2; ++i)
#pragma unroll
    for (int j = 0; j < 2; ++j) acc[i][j] = (f32x4){0, 0, 0, 0};

  const int ar0 = wr * 32 + lo, br0 = wc * 32 + lo;
#pragma unroll
  for (int kk = 0; kk < 8; ++kk) {
    int kc = kk * 32 + g * 8;
    short8 a0 = *(const short8*)&As[ar0][kc];
    short8 a1 = *(const short8*)&As[ar0 + 16][kc];
    short8 b0 = *(const short8*)&Bs[br0][kc];
    short8 b1 = *(const short8*)&Bs[br0 + 16][kc];
    acc[0][0] = __builtin_amdgcn_mfma_f32_16x16x32_bf16(a0, b0, acc[0][0], 0, 0, 0);
    acc[0][1] = __builtin_amdgcn_mfma_f32_16x16x32_bf16(a0, b1, acc[0][1], 0, 0, 0);
    acc[1][0] = __builtin_amdgcn_mfma_f32_16x16x32_bf16(a1, b0, acc[1][0], 0, 0, 0);
    acc[1][1] = __builtin_amdgcn_mfma_f32_16x16x32_bf16(a1, b1, acc[1][1], 0, 0, 0);
  }

  const float qs = (EPI == 0 && row0 < 256) ? K1S : 1.0f;
#pragma unroll
  for (int m2 = 0; m2 < 2; ++m2)
#pragma unroll
    for (int n2 = 0; n2 < 2; ++n2) {
      int m = row0 + wr * 32 + m2 * 16 + g * 4;
      int n = col0 + wc * 32 + n2 * 16 + lo;
      if constexpr (EPI == 0) {
        if (row0 < 512) {  // q,k -> transposed qkT[b][n][m..m+3]
          u16x4 pk = {f2bf(acc[m2][n2][0] * qs), f2bf(acc[m2][n2][1] * qs),
                      f2bf(acc[m2][n2][2] * qs), f2bf(acc[m2][n2][3] * qs)};
          *(u16x4*)(qkT + ((size_t)b * NSP + n) * 512 + m) = pk;
        } else {           // v -> natural vbuf[b][m-512][n]
#pragma unroll
          for (int r = 0; r < 4; ++r)
            vbuf[((size_t)b * 256 + (m - 512 + r)) * NSP + n] =
                f2bf(acc[m2][n2][r]);
        }
      } else {
#pragma unroll
        for (int r = 0; r < 4; ++r)
          outf[((size_t)b * 256 + m + r) * NSP + n] =
              acc[m2][n2][r] + bias[m + r];
      }
    }
}

// ---------------------------------------------------------------------------
// MFMA flash attention. 128-thread 2-wave blocks; each wave owns 32 queries
// (two 16-q B-fragments) so the shared K/V LDS fragments (wave-independent
// under swapped-S) are reused 2x per read. P never touches LDS (r8's sigma
// trick); P packing via v_cvt_pk_bf16_f32. Vs stride 68 u16 (34 dw == 2 mod
// 32) -> V b64 frag reads + staging writes conflict-free; Kt stride 40
// (20 dw) conflict-free for b128 reads. Row-sum l via ones-MFMA.
// ---------------------------------------------------------------------------
__global__ __launch_bounds__(128) void attn_mfma(
    const u16* __restrict__ qkT, const u16* __restrict__ vbuf,
    u16* __restrict__ attnoT) {
  const int it = blockIdx.x, h = blockIdx.y, b = blockIdx.z;
  const int t = threadIdx.x, lane = t & 63, w = t >> 6;
  const int lo = lane & 15, g = lane >> 4;
  const int i0 = it * 64;

  const u16* qkTb = qkT + (size_t)b * NSP * 512;
  const u16* vb   = vbuf + ((size_t)b * 256 + h * 32) * NSP;
  u16* ob = attnoT + ((size_t)b * NSP + i0) * 256 + h * 32;

  __shared__ u16 Kt[2][64][40];   // [j][d]
  __shared__ u16 Vs[2][32][68];   // [d][j]

  // two Q fragments: queries i0 + w*32 + qh*16 + lo (pre-scaled by K1S)
  short8 qfA = *(const short8*)(qkTb + (size_t)(i0 + w * 32 + lo) * 512 +
                                h * 32 + g * 8);
  short8 qfB = *(const short8*)(qkTb + (size_t)(i0 + w * 32 + 16 + lo) * 512 +
                                h * 32 + g * 8);

  // staging (128 thr): K rows kr, kr+32 (16B each); V rows vr, vr+16
  const int kr = t >> 2, kp = (t & 3) * 8;
  const int vr = t >> 3, vp = (t & 7) * 8;
  const u16* ksrc  = qkTb + 256 + h * 32 + kp;            // + row*512
  const u16* vsrc0 = vb + (size_t)vr * NSP + vp;          // + j0
  const u16* vsrc1 = vb + (size_t)(vr + 16) * NSP + vp;

  uint4 k0 = *(const uint4*)(ksrc + (size_t)kr * 512);
  uint4 k1 = *(const uint4*)(ksrc + (size_t)(kr + 32) * 512);
  uint4 v0 = *(const uint4*)(vsrc0);
  uint4 v1 = *(const uint4*)(vsrc1);
  *(uint4*)&Kt[0][kr][kp]      = k0;
  *(uint4*)&Kt[0][kr + 32][kp] = k1;
  *(uint4*)&Vs[0][vr][vp]      = v0;
  *(uint4*)&Vs[0][vr + 16][vp] = v1;
  __syncthreads();

  short8 ones;
#pragma unroll
  for (int e = 0; e < 8; ++e) ones[e] = (short)0x3F80;  // bf16 1.0

  f32x4 a0A = {0, 0, 0, 0}, a1A = {0, 0, 0, 0}, alA = {0, 0, 0, 0};
  f32x4 a0B = {0, 0, 0, 0}, a1B = {0, 0, 0, 0}, alB = {0, 0, 0, 0};

  for (int s = 0; s < 36; ++s) {
    const int cur = s & 1;
    if (s + 1 < 36) {  // prefetch next strip into regs
      int j0n = (s + 1) * 64;
      k0 = *(const uint4*)(ksrc + (size_t)(j0n + kr) * 512);
      k1 = *(const uint4*)(ksrc + (size_t)(j0n + kr + 32) * 512);
      v0 = *(const uint4*)(vsrc0 + j0n);
      v1 = *(const uint4*)(vsrc1 + j0n);
    }

    // ---- K fragments (shared by both q-halves) ----
    short8 kf0 = *(const short8*)&Kt[cur][lo][g * 8];
    short8 kf1 = *(const short8*)&Kt[cur][16 + lo][g * 8];
    short8 kf2 = *(const short8*)&Kt[cur][32 + lo][g * 8];
    short8 kf3 = *(const short8*)&Kt[cur][48 + lo][g * 8];
    // ---- V fragments under sigma (shared by both q-halves) ----
    short4v v00a = *(const short4v*)&Vs[cur][lo][4 * g];
    short4v v00b = *(const short4v*)&Vs[cur][lo][16 + 4 * g];
    short4v v01a = *(const short4v*)&Vs[cur][lo][32 + 4 * g];
    short4v v01b = *(const short4v*)&Vs[cur][lo][48 + 4 * g];
    short4v v10a = *(const short4v*)&Vs[cur][16 + lo][4 * g];
    short4v v10b = *(const short4v*)&Vs[cur][16 + lo][16 + 4 * g];
    short4v v11a = *(const short4v*)&Vs[cur][16 + lo][32 + 4 * g];
    short4v v11b = *(const short4v*)&Vs[cur][16 + lo][48 + 4 * g];
    short8 vf00 = __builtin_shufflevector(v00a, v00b, 0, 1, 2, 3, 4, 5, 6, 7);
    short8 vf01 = __builtin_shufflevector(v01a, v01b, 0, 1, 2, 3, 4, 5, 6, 7);
    short8 vf10 = __builtin_shufflevector(v10a, v10b, 0, 1, 2, 3, 4, 5, 6, 7);
    short8 vf11 = __builtin_shufflevector(v11a, v11b, 0, 1, 2, 3, 4, 5, 6, 7);

#pragma unroll
    for (int qh = 0; qh < 2; ++qh) {
      short8 qf = qh ? qfB : qfA;
      // ---- S^T = mfma(K, Q): lane holds S[j=16jt+4g+r][q=lo] ----
      f32x4 sv0 = __builtin_amdgcn_mfma_f32_16x16x32_bf16(kf0, qf, (f32x4){0,0,0,0}, 0, 0, 0);
      f32x4 sv1 = __builtin_amdgcn_mfma_f32_16x16x32_bf16(kf1, qf, (f32x4){0,0,0,0}, 0, 0, 0);
      f32x4 sv2 = __builtin_amdgcn_mfma_f32_16x16x32_bf16(kf2, qf, (f32x4){0,0,0,0}, 0, 0, 0);
      f32x4 sv3 = __builtin_amdgcn_mfma_f32_16x16x32_bf16(kf3, qf, (f32x4){0,0,0,0}, 0, 0, 0);

      // ---- p = exp2(S), packed in-register (v_cvt_pk_bf16_f32) ----
      f32x4 e0, e1, e2, e3;
#pragma unroll
      for (int r = 0; r < 4; ++r) {
        e0[r] = __builtin_amdgcn_exp2f(sv0[r]);
        e1[r] = __builtin_amdgcn_exp2f(sv1[r]);
        e2[r] = __builtin_amdgcn_exp2f(sv2[r]);
        e3[r] = __builtin_amdgcn_exp2f(sv3[r]);
      }
      uint4 P0 = {cvtpk(e0[0], e0[1]), cvtpk(e0[2], e0[3]),
                  cvtpk(e1[0], e1[1]), cvtpk(e1[2], e1[3])};
      uint4 P1 = {cvtpk(e2[0], e2[1]), cvtpk(e2[2], e2[3]),
                  cvtpk(e3[0], e3[1]), cvtpk(e3[2], e3[3])};
      short8 pf0 = __builtin_bit_cast(short8, P0);
      short8 pf1 = __builtin_bit_cast(short8, P1);

      // ---- PV + row-sum l (all MFMA) ----
      f32x4& c0 = qh ? a0B : a0A;
      f32x4& c1 = qh ? a1B : a1A;
      f32x4& cl = qh ? alB : alA;
      c0 = __builtin_amdgcn_mfma_f32_16x16x32_bf16(pf0, vf00, c0, 0, 0, 0);
      c1 = __builtin_amdgcn_mfma_f32_16x16x32_bf16(pf0, vf10, c1, 0, 0, 0);
      cl = __builtin_amdgcn_mfma_f32_16x16x32_bf16(pf0, ones, cl, 0, 0, 0);
      c0 = __builtin_amdgcn_mfma_f32_16x16x32_bf16(pf1, vf01, c0, 0, 0, 0);
      c1 = __builtin_amdgcn_mfma_f32_16x16x32_bf16(pf1, vf11, c1, 0, 0, 0);
      cl = __builtin_amdgcn_mfma_f32_16x16x32_bf16(pf1, ones, cl, 0, 0, 0);
    }

    if (s + 1 < 36) {  // write next strip into the other buffer
      *(uint4*)&Kt[cur ^ 1][kr][kp]      = k0;
      *(uint4*)&Kt[cur ^ 1][kr + 32][kp] = k1;
      *(uint4*)&Vs[cur ^ 1][vr][vp]      = v0;
      *(uint4*)&Vs[cur ^ 1][vr + 16][vp] = v1;
    }
    __syncthreads();
  }

  // ---- normalize + bf16 store to attnoT[n][c] ----
#pragma unroll
  for (int qh = 0; qh < 2; ++qh) {
    f32x4 c0 = qh ? a0B : a0A;
    f32x4 c1 = qh ? a1B : a1A;
    f32x4 cl = qh ? alB : alA;
#pragma unroll
    for (int r = 0; r < 4; ++r) {
      float inv = 1.0f / cl[r];
      int row = w * 32 + qh * 16 + g * 4 + r;
      ob[(size_t)row * 256 + lo]      = f2bf(c0[r] * inv);
      ob[(size_t)row * 256 + 16 + lo] = f2bf(c1[r] * inv);
    }
  }
}

// ---------------------------------------------------------------------------
extern "C" void kernel_launch(void* const* d_in, const int* in_sizes, int n_in,
                              void* d_out, int out_size, void* d_ws, size_t ws_size,
                              hipStream_t stream) {
  const float* x     = (const float*)d_in[0];  // [4][256][48][48]
  const float* w_qkv = (const float*)d_in[1];  // [768][256]
  const float* w_out = (const float*)d_in[2];  // [256][256]
  const float* b_out = (const float*)d_in[3];  // [256]
  float* out = (float*)d_out;                  // [4][256][2304]

  u16* wbf    = (u16*)d_ws;                    // wqkv 196608 then wout 65536
  u16* xT     = wbf + 262144;                  // [4][2304][256]
  u16* qkT    = xT + (size_t)NB * NSP * 256;   // [4][2304][512]
  u16* vbuf   = qkT + (size_t)NB * NSP * 512;  // [4][256][2304]
  u16* attnoT = vbuf + (size_t)NB * 256 * NSP; // [4][2304][256]

  dim3 blk(256);
  convert_w<<<256, blk, 0, stream>>>(w_qkv, w_out, wbf);
  transpose_x<<<dim3(NSP / 32, 8, NB), blk, 0, stream>>>(x, xT);
  gemm_mfma<0><<<dim3(NSP / 64, 12, NB), blk, 0, stream>>>(
      wbf, xT, qkT, vbuf, nullptr, nullptr, NSP);
  attn_mfma<<<dim3(NSP / 64, 8, NB), dim3(128), 0, stream>>>(qkT, vbuf, attnoT);
  gemm_mfma<1><<<dim3(NSP / 64, 4, NB), blk, 0, stream>>>(
      wbf + 196608, attnoT, nullptr, nullptr, out, b_out, NSP);
}

// Round 10
// 80.336 us; speedup vs baseline: 1.9073x; 1.0145x over previous
//
#include <hip/hip_runtime.h>
#include <hip/hip_bf16.h>

#define NSP 2304   // 48*48 spatial
#define NB  4      // batch

typedef unsigned short u16;
typedef __attribute__((ext_vector_type(8))) short short8;
typedef __attribute__((ext_vector_type(4))) short short4v;
typedef __attribute__((ext_vector_type(4))) float f32x4;
typedef __attribute__((ext_vector_type(4))) unsigned short u16x4;

// scale * log2(e), folded into Q at QKV-GEMM epilogue: softmax p = exp2(S)
#define K1S 0.25508040852656425f

static __device__ inline u16 f2bf(float f) {
  return __builtin_bit_cast(unsigned short, __float2bfloat16(f));
}
// packed f32x2 -> bf16x2 (RNE), single VALU inst; lo16 = cvt(a), hi16 = cvt(b)
static __device__ inline unsigned cvtpk(float a, float b) {
  unsigned r;
  asm("v_cvt_pk_bf16_f32 %0, %1, %2" : "=v"(r) : "v"(a), "v"(b));
  return r;
}

// ---------------------------------------------------------------------------
// prep 1: w_qkv (768*256) and w_out (256*256) fp32 -> bf16, one region.
// ---------------------------------------------------------------------------
__global__ __launch_bounds__(256) void convert_w(
    const float* __restrict__ wq, const float* __restrict__ wo,
    u16* __restrict__ dst) {
  int i = (blockIdx.x * 256 + threadIdx.x) * 4;
  float4 v;
  if (i < 196608) v = *(const float4*)(wq + i);
  else            v = *(const float4*)(wo + (i - 196608));
  u16x4 p = {f2bf(v.x), f2bf(v.y), f2bf(v.z), f2bf(v.w)};
  *(u16x4*)(dst + i) = p;
}

// ---------------------------------------------------------------------------
// prep 2: x fp32 [b][256][2304] -> xT bf16 [b][2304][256]
// ---------------------------------------------------------------------------
__global__ __launch_bounds__(256) void transpose_x(
    const float* __restrict__ x, u16* __restrict__ xT) {
  __shared__ float tile[32][33];
  const int t = threadIdx.x;
  const int n0 = blockIdx.x * 32, c0 = blockIdx.y * 32, b = blockIdx.z;
  const float* xb = x + ((size_t)b * 256 + c0) * NSP + n0;
#pragma unroll
  for (int e = t; e < 1024; e += 256) {
    int cc = e >> 5, nn = e & 31;
    tile[cc][nn] = xb[(size_t)cc * NSP + nn];
  }
  __syncthreads();
  u16* xTb = xT + ((size_t)b * NSP + n0) * 256 + c0;
#pragma unroll
  for (int e = t; e < 1024; e += 256) {
    int nn = e >> 5, cc = e & 31;
    xTb[(size_t)nn * 256 + cc] = f2bf(tile[cc][nn]);
  }
}

// ---------------------------------------------------------------------------
// bf16 MFMA GEMM (LDS-staged): D = A (Mx256) * B[b](Nx256)^T
// 64x64 tile, 4 waves (2x2 of 32x32), whole K=256 staged once.
// EPI 0: rows <256 q (pre-scaled K1S), 256..511 k -> qkT[b][n][512] bf16;
//        rows >=512 v -> vbuf[b][256][2304] bf16.
// EPI 1: fp32 out + bias.
// ---------------------------------------------------------------------------
template <int EPI>
__global__ __launch_bounds__(256) void gemm_mfma(
    const u16* __restrict__ A, const u16* __restrict__ B,
    u16* __restrict__ qkT, u16* __restrict__ vbuf,
    float* __restrict__ outf, const float* __restrict__ bias, int N) {
  __shared__ u16 As[64][264];
  __shared__ u16 Bs[64][264];
  const int t = threadIdx.x, lane = t & 63, wid = t >> 6;
  const int lo = lane & 15, g = lane >> 4;
  const int wr = wid >> 1, wc = wid & 1;
  const int row0 = blockIdx.y * 64, col0 = blockIdx.x * 64, b = blockIdx.z;

  const int sr = t >> 2, c4 = t & 3;
  const u16* Arow = A + (size_t)(row0 + sr) * 256;
  const u16* Brow = B + ((size_t)b * N + col0 + sr) * 256;
#pragma unroll
  for (int i = 0; i < 8; ++i) {
    int col = (c4 + 4 * i) * 8;
    *(uint4*)&As[sr][col] = *(const uint4*)&Arow[col];
    *(uint4*)&Bs[sr][col] = *(const uint4*)&Brow[col];
  }
  __syncthreads();

  f32x4 acc[2][2];
#pragma unroll
  for (int i = 0; i < 2; ++i)
#pragma unroll
    for (int j = 0; j < 2; ++j) acc[i][j] = (f32x4){0, 0, 0, 0};

  const int ar0 = wr * 32 + lo, br0 = wc * 32 + lo;
#pragma unroll
  for (int kk = 0; kk < 8; ++kk) {
    int kc = kk * 32 + g * 8;
    short8 a0 = *(const short8*)&As[ar0][kc];
    short8 a1 = *(const short8*)&As[ar0 + 16][kc];
    short8 b0 = *(const short8*)&Bs[br0][kc];
    short8 b1 = *(const short8*)&Bs[br0 + 16][kc];
    acc[0][0] = __builtin_amdgcn_mfma_f32_16x16x32_bf16(a0, b0, acc[0][0], 0, 0, 0);
    acc[0][1] = __builtin_amdgcn_mfma_f32_16x16x32_bf16(a0, b1, acc[0][1], 0, 0, 0);
    acc[1][0] = __builtin_amdgcn_mfma_f32_16x16x32_bf16(a1, b0, acc[1][0], 0, 0, 0);
    acc[1][1] = __builtin_amdgcn_mfma_f32_16x16x32_bf16(a1, b1, acc[1][1], 0, 0, 0);
  }

  const float qs = (EPI == 0 && row0 < 256) ? K1S : 1.0f;
#pragma unroll
  for (int m2 = 0; m2 < 2; ++m2)
#pragma unroll
    for (int n2 = 0; n2 < 2; ++n2) {
      int m = row0 + wr * 32 + m2 * 16 + g * 4;
      int n = col0 + wc * 32 + n2 * 16 + lo;
      if constexpr (EPI == 0) {
        if (row0 < 512) {  // q,k -> transposed qkT[b][n][m..m+3]
          u16x4 pk = {f2bf(acc[m2][n2][0] * qs), f2bf(acc[m2][n2][1] * qs),
                      f2bf(acc[m2][n2][2] * qs), f2bf(acc[m2][n2][3] * qs)};
          *(u16x4*)(qkT + ((size_t)b * NSP + n) * 512 + m) = pk;
        } else {           // v -> natural vbuf[b][m-512][n]
#pragma unroll
          for (int r = 0; r < 4; ++r)
            vbuf[((size_t)b * 256 + (m - 512 + r)) * NSP + n] =
                f2bf(acc[m2][n2][r]);
        }
      } else {
#pragma unroll
        for (int r = 0; r < 4; ++r)
          outf[((size_t)b * 256 + m + r) * NSP + n] =
              acc[m2][n2][r] + bias[m + r];
      }
    }
}

// ---------------------------------------------------------------------------
// MFMA flash attention, XCD-SWIZZLED 1-D grid (1152 blocks).
// Block decode: pair = (b,h) group; j = 8*((pair>>3)*36 + it) + (pair&7)
// => XCD(j) = j%8 = h, so all 36 query-tiles of one (b,h) (sharing ~300 KB
// of K/V) land on ONE XCD; per-XCD L2 set = 4 pairs ~ 1.2 MB (resident).
// Kernel body identical to r9: 2-wave 128-thr, 32 q/wave, P in-register
// (sigma trick), Vs stride 68 / Kt stride 40 conflict-free, ones-MFMA l.
// ---------------------------------------------------------------------------
__global__ __launch_bounds__(128) void attn_mfma(
    const u16* __restrict__ qkT, const u16* __restrict__ vbuf,
    u16* __restrict__ attnoT) {
  const int j = blockIdx.x;
  const int h = j & 7;
  const int q = j >> 3;
  const int it = q % 36;
  const int b  = q / 36;
  const int t = threadIdx.x, lane = t & 63, w = t >> 6;
  const int lo = lane & 15, g = lane >> 4;
  const int i0 = it * 64;

  const u16* qkTb = qkT + (size_t)b * NSP * 512;
  const u16* vb   = vbuf + ((size_t)b * 256 + h * 32) * NSP;
  u16* ob = attnoT + ((size_t)b * NSP + i0) * 256 + h * 32;

  __shared__ u16 Kt[2][64][40];   // [j][d]
  __shared__ u16 Vs[2][32][68];   // [d][j]

  // two Q fragments: queries i0 + w*32 + qh*16 + lo (pre-scaled by K1S)
  short8 qfA = *(const short8*)(qkTb + (size_t)(i0 + w * 32 + lo) * 512 +
                                h * 32 + g * 8);
  short8 qfB = *(const short8*)(qkTb + (size_t)(i0 + w * 32 + 16 + lo) * 512 +
                                h * 32 + g * 8);

  // staging (128 thr): K rows kr, kr+32 (16B each); V rows vr, vr+16
  const int kr = t >> 2, kp = (t & 3) * 8;
  const int vr = t >> 3, vp = (t & 7) * 8;
  const u16* ksrc  = qkTb + 256 + h * 32 + kp;            // + row*512
  const u16* vsrc0 = vb + (size_t)vr * NSP + vp;          // + j0
  const u16* vsrc1 = vb + (size_t)(vr + 16) * NSP + vp;

  uint4 k0 = *(const uint4*)(ksrc + (size_t)kr * 512);
  uint4 k1 = *(const uint4*)(ksrc + (size_t)(kr + 32) * 512);
  uint4 v0 = *(const uint4*)(vsrc0);
  uint4 v1 = *(const uint4*)(vsrc1);
  *(uint4*)&Kt[0][kr][kp]      = k0;
  *(uint4*)&Kt[0][kr + 32][kp] = k1;
  *(uint4*)&Vs[0][vr][vp]      = v0;
  *(uint4*)&Vs[0][vr + 16][vp] = v1;
  __syncthreads();

  short8 ones;
#pragma unroll
  for (int e = 0; e < 8; ++e) ones[e] = (short)0x3F80;  // bf16 1.0

  f32x4 a0A = {0, 0, 0, 0}, a1A = {0, 0, 0, 0}, alA = {0, 0, 0, 0};
  f32x4 a0B = {0, 0, 0, 0}, a1B = {0, 0, 0, 0}, alB = {0, 0, 0, 0};

  for (int s = 0; s < 36; ++s) {
    const int cur = s & 1;
    if (s + 1 < 36) {  // prefetch next strip into regs
      int j0n = (s + 1) * 64;
      k0 = *(const uint4*)(ksrc + (size_t)(j0n + kr) * 512);
      k1 = *(const uint4*)(ksrc + (size_t)(j0n + kr + 32) * 512);
      v0 = *(const uint4*)(vsrc0 + j0n);
      v1 = *(const uint4*)(vsrc1 + j0n);
    }

    // ---- K fragments (shared by both q-halves) ----
    short8 kf0 = *(const short8*)&Kt[cur][lo][g * 8];
    short8 kf1 = *(const short8*)&Kt[cur][16 + lo][g * 8];
    short8 kf2 = *(const short8*)&Kt[cur][32 + lo][g * 8];
    short8 kf3 = *(const short8*)&Kt[cur][48 + lo][g * 8];
    // ---- V fragments under sigma (shared by both q-halves) ----
    short4v v00a = *(const short4v*)&Vs[cur][lo][4 * g];
    short4v v00b = *(const short4v*)&Vs[cur][lo][16 + 4 * g];
    short4v v01a = *(const short4v*)&Vs[cur][lo][32 + 4 * g];
    short4v v01b = *(const short4v*)&Vs[cur][lo][48 + 4 * g];
    short4v v10a = *(const short4v*)&Vs[cur][16 + lo][4 * g];
    short4v v10b = *(const short4v*)&Vs[cur][16 + lo][16 + 4 * g];
    short4v v11a = *(const short4v*)&Vs[cur][16 + lo][32 + 4 * g];
    short4v v11b = *(const short4v*)&Vs[cur][16 + lo][48 + 4 * g];
    short8 vf00 = __builtin_shufflevector(v00a, v00b, 0, 1, 2, 3, 4, 5, 6, 7);
    short8 vf01 = __builtin_shufflevector(v01a, v01b, 0, 1, 2, 3, 4, 5, 6, 7);
    short8 vf10 = __builtin_shufflevector(v10a, v10b, 0, 1, 2, 3, 4, 5, 6, 7);
    short8 vf11 = __builtin_shufflevector(v11a, v11b, 0, 1, 2, 3, 4, 5, 6, 7);

#pragma unroll
    for (int qh = 0; qh < 2; ++qh) {
      short8 qf = qh ? qfB : qfA;
      // ---- S^T = mfma(K, Q): lane holds S[j=16jt+4g+r][q=lo] ----
      f32x4 sv0 = __builtin_amdgcn_mfma_f32_16x16x32_bf16(kf0, qf, (f32x4){0,0,0,0}, 0, 0, 0);
      f32x4 sv1 = __builtin_amdgcn_mfma_f32_16x16x32_bf16(kf1, qf, (f32x4){0,0,0,0}, 0, 0, 0);
      f32x4 sv2 = __builtin_amdgcn_mfma_f32_16x16x32_bf16(kf2, qf, (f32x4){0,0,0,0}, 0, 0, 0);
      f32x4 sv3 = __builtin_amdgcn_mfma_f32_16x16x32_bf16(kf3, qf, (f32x4){0,0,0,0}, 0, 0, 0);

      // ---- p = exp2(S), packed in-register (v_cvt_pk_bf16_f32) ----
      f32x4 e0, e1, e2, e3;
#pragma unroll
      for (int r = 0; r < 4; ++r) {
        e0[r] = __builtin_amdgcn_exp2f(sv0[r]);
        e1[r] = __builtin_amdgcn_exp2f(sv1[r]);
        e2[r] = __builtin_amdgcn_exp2f(sv2[r]);
        e3[r] = __builtin_amdgcn_exp2f(sv3[r]);
      }
      uint4 P0 = {cvtpk(e0[0], e0[1]), cvtpk(e0[2], e0[3]),
                  cvtpk(e1[0], e1[1]), cvtpk(e1[2], e1[3])};
      uint4 P1 = {cvtpk(e2[0], e2[1]), cvtpk(e2[2], e2[3]),
                  cvtpk(e3[0], e3[1]), cvtpk(e3[2], e3[3])};
      short8 pf0 = __builtin_bit_cast(short8, P0);
      short8 pf1 = __builtin_bit_cast(short8, P1);

      // ---- PV + row-sum l (all MFMA) ----
      f32x4& c0 = qh ? a0B : a0A;
      f32x4& c1 = qh ? a1B : a1A;
      f32x4& cl = qh ? alB : alA;
      c0 = __builtin_amdgcn_mfma_f32_16x16x32_bf16(pf0, vf00, c0, 0, 0, 0);
      c1 = __builtin_amdgcn_mfma_f32_16x16x32_bf16(pf0, vf10, c1, 0, 0, 0);
      cl = __builtin_amdgcn_mfma_f32_16x16x32_bf16(pf0, ones, cl, 0, 0, 0);
      c0 = __builtin_amdgcn_mfma_f32_16x16x32_bf16(pf1, vf01, c0, 0, 0, 0);
      c1 = __builtin_amdgcn_mfma_f32_16x16x32_bf16(pf1, vf11, c1, 0, 0, 0);
      cl = __builtin_amdgcn_mfma_f32_16x16x32_bf16(pf1, ones, cl, 0, 0, 0);
    }

    if (s + 1 < 36) {  // write next strip into the other buffer
      *(uint4*)&Kt[cur ^ 1][kr][kp]      = k0;
      *(uint4*)&Kt[cur ^ 1][kr + 32][kp] = k1;
      *(uint4*)&Vs[cur ^ 1][vr][vp]      = v0;
      *(uint4*)&Vs[cur ^ 1][vr + 16][vp] = v1;
    }
    __syncthreads();
  }

  // ---- normalize + bf16 store to attnoT[n][c] ----
#pragma unroll
  for (int qh = 0; qh < 2; ++qh) {
    f32x4 c0 = qh ? a0B : a0A;
    f32x4 c1 = qh ? a1B : a1A;
    f32x4 cl = qh ? alB : alA;
#pragma unroll
    for (int r = 0; r < 4; ++r) {
      float inv = 1.0f / cl[r];
      int row = w * 32 + qh * 16 + g * 4 + r;
      ob[(size_t)row * 256 + lo]      = f2bf(c0[r] * inv);
      ob[(size_t)row * 256 + 16 + lo] = f2bf(c1[r] * inv);
    }
  }
}

// ---------------------------------------------------------------------------
extern "C" void kernel_launch(void* const* d_in, const int* in_sizes, int n_in,
                              void* d_out, int out_size, void* d_ws, size_t ws_size,
                              hipStream_t stream) {
  const float* x     = (const float*)d_in[0];  // [4][256][48][48]
  const float* w_qkv = (const float*)d_in[1];  // [768][256]
  const float* w_out = (const float*)d_in[2];  // [256][256]
  const float* b_out = (const float*)d_in[3];  // [256]
  float* out = (float*)d_out;                  // [4][256][2304]

  u16* wbf    = (u16*)d_ws;                    // wqkv 196608 then wout 65536
  u16* xT     = wbf + 262144;                  // [4][2304][256]
  u16* qkT    = xT + (size_t)NB * NSP * 256;   // [4][2304][512]
  u16* vbuf   = qkT + (size_t)NB * NSP * 512;  // [4][256][2304]
  u16* attnoT = vbuf + (size_t)NB * 256 * NSP; // [4][2304][256]

  dim3 blk(256);
  convert_w<<<256, blk, 0, stream>>>(w_qkv, w_out, wbf);
  transpose_x<<<dim3(NSP / 32, 8, NB), blk, 0, stream>>>(x, xT);
  gemm_mfma<0><<<dim3(NSP / 64, 12, NB), blk, 0, stream>>>(
      wbf, xT, qkT, vbuf, nullptr, nullptr, NSP);
  attn_mfma<<<dim3(1152), dim3(128), 0, stream>>>(qkT, vbuf, attnoT);
  gemm_mfma<1><<<dim3(NSP / 64, 4, NB), blk, 0, stream>>>(
      wbf + 196608, attnoT, nullptr, nullptr, out, b_out, NSP);
}

// Round 11
// 75.617 us; speedup vs baseline: 2.0263x; 1.0624x over previous
//
#include <hip/hip_runtime.h>
#include <hip/hip_bf16.h>

#define NSP 2304   // 48*48 spatial
#define NB  4      // batch

typedef unsigned short u16;
typedef __attribute__((ext_vector_type(8))) short short8;
typedef __attribute__((ext_vector_type(4))) float f32x4;
typedef __attribute__((ext_vector_type(4))) unsigned short u16x4;

// scale * log2(e), folded into Q at QKV-GEMM epilogue: softmax p = exp2(S)
#define K1S 0.25508040852656425f

static __device__ inline u16 f2bf(float f) {
  return __builtin_bit_cast(unsigned short, __float2bfloat16(f));
}
// packed f32x2 -> bf16x2 (RNE), single VALU inst; lo16 = cvt(a), hi16 = cvt(b)
static __device__ inline unsigned cvtpk(float a, float b) {
  unsigned r;
  asm("v_cvt_pk_bf16_f32 %0, %1, %2" : "=v"(r) : "v"(a), "v"(b));
  return r;
}

// ---------------------------------------------------------------------------
// prep 1: w_qkv (768*256) and w_out (256*256) fp32 -> bf16, one region.
// ---------------------------------------------------------------------------
__global__ __launch_bounds__(256) void convert_w(
    const float* __restrict__ wq, const float* __restrict__ wo,
    u16* __restrict__ dst) {
  int i = (blockIdx.x * 256 + threadIdx.x) * 4;
  float4 v;
  if (i < 196608) v = *(const float4*)(wq + i);
  else            v = *(const float4*)(wo + (i - 196608));
  u16x4 p = {f2bf(v.x), f2bf(v.y), f2bf(v.z), f2bf(v.w)};
  *(u16x4*)(dst + i) = p;
}

// ---------------------------------------------------------------------------
// prep 2: x fp32 [b][256][2304] -> xT bf16 [b][2304][256]
// ---------------------------------------------------------------------------
__global__ __launch_bounds__(256) void transpose_x(
    const float* __restrict__ x, u16* __restrict__ xT) {
  __shared__ float tile[32][33];
  const int t = threadIdx.x;
  const int n0 = blockIdx.x * 32, c0 = blockIdx.y * 32, b = blockIdx.z;
  const float* xb = x + ((size_t)b * 256 + c0) * NSP + n0;
#pragma unroll
  for (int e = t; e < 1024; e += 256) {
    int cc = e >> 5, nn = e & 31;
    tile[cc][nn] = xb[(size_t)cc * NSP + nn];
  }
  __syncthreads();
  u16* xTb = xT + ((size_t)b * NSP + n0) * 256 + c0;
#pragma unroll
  for (int e = t; e < 1024; e += 256) {
    int nn = e >> 5, cc = e & 31;
    xTb[(size_t)nn * 256 + cc] = f2bf(tile[cc][nn]);
  }
}

// ---------------------------------------------------------------------------
// bf16 MFMA GEMM (LDS-staged): D = A (Mx256) * B[b](Nx256)^T
// 64x64 tile, 4 waves (2x2 of 32x32), whole K=256 staged once.
// EPI 0: rows <256 q (pre-scaled K1S), 256..511 k -> qkT[b][n][512] bf16;
//        rows >=512 v -> vbuf[b][256][2304] bf16.
// EPI 1: fp32 out + bias.
// ---------------------------------------------------------------------------
template <int EPI>
__global__ __launch_bounds__(256) void gemm_mfma(
    const u16* __restrict__ A, const u16* __restrict__ B,
    u16* __restrict__ qkT, u16* __restrict__ vbuf,
    float* __restrict__ outf, const float* __restrict__ bias, int N) {
  __shared__ u16 As[64][264];
  __shared__ u16 Bs[64][264];
  const int t = threadIdx.x, lane = t & 63, wid = t >> 6;
  const int lo = lane & 15, g = lane >> 4;
  const int wr = wid >> 1, wc = wid & 1;
  const int row0 = blockIdx.y * 64, col0 = blockIdx.x * 64, b = blockIdx.z;

  const int sr = t >> 2, c4 = t & 3;
  const u16* Arow = A + (size_t)(row0 + sr) * 256;
  const u16* Brow = B + ((size_t)b * N + col0 + sr) * 256;
#pragma unroll
  for (int i = 0; i < 8; ++i) {
    int col = (c4 + 4 * i) * 8;
    *(uint4*)&As[sr][col] = *(const uint4*)&Arow[col];
    *(uint4*)&Bs[sr][col] = *(const uint4*)&Brow[col];
  }
  __syncthreads();

  f32x4 acc[2][2];
#pragma unroll
  for (int i = 0; i < 2; ++i)
#pragma unroll
    for (int j = 0; j < 2; ++j) acc[i][j] = (f32x4){0, 0, 0, 0};

  const int ar0 = wr * 32 + lo, br0 = wc * 32 + lo;
#pragma unroll
  for (int kk = 0; kk < 8; ++kk) {
    int kc = kk * 32 + g * 8;
    short8 a0 = *(const short8*)&As[ar0][kc];
    short8 a1 = *(const short8*)&As[ar0 + 16][kc];
    short8 b0 = *(const short8*)&Bs[br0][kc];
    short8 b1 = *(const short8*)&Bs[br0 + 16][kc];
    acc[0][0] = __builtin_amdgcn_mfma_f32_16x16x32_bf16(a0, b0, acc[0][0], 0, 0, 0);
    acc[0][1] = __builtin_amdgcn_mfma_f32_16x16x32_bf16(a0, b1, acc[0][1], 0, 0, 0);
    acc[1][0] = __builtin_amdgcn_mfma_f32_16x16x32_bf16(a1, b0, acc[1][0], 0, 0, 0);
    acc[1][1] = __builtin_amdgcn_mfma_f32_16x16x32_bf16(a1, b1, acc[1][1], 0, 0, 0);
  }

  const float qs = (EPI == 0 && row0 < 256) ? K1S : 1.0f;
#pragma unroll
  for (int m2 = 0; m2 < 2; ++m2)
#pragma unroll
    for (int n2 = 0; n2 < 2; ++n2) {
      int m = row0 + wr * 32 + m2 * 16 + g * 4;
      int n = col0 + wc * 32 + n2 * 16 + lo;
      if constexpr (EPI == 0) {
        if (row0 < 512) {  // q,k -> transposed qkT[b][n][m..m+3]
          u16x4 pk = {f2bf(acc[m2][n2][0] * qs), f2bf(acc[m2][n2][1] * qs),
                      f2bf(acc[m2][n2][2] * qs), f2bf(acc[m2][n2][3] * qs)};
          *(u16x4*)(qkT + ((size_t)b * NSP + n) * 512 + m) = pk;
        } else {           // v -> natural vbuf[b][m-512][n]
#pragma unroll
          for (int r = 0; r < 4; ++r)
            vbuf[((size_t)b * 256 + (m - 512 + r)) * NSP + n] =
                f2bf(acc[m2][n2][r]);
        }
      } else {
#pragma unroll
        for (int r = 0; r < 4; ++r)
          outf[((size_t)b * 256 + m + r) * NSP + n] =
              acc[m2][n2][r] + bias[m + r];
      }
    }
}

// ---------------------------------------------------------------------------
// MFMA flash attention, issue-count-optimized.
// 2-wave 128-thr blocks, 48 queries/wave (3 Q-frags) -> K/V fragment reads
// amortized 3x. KVBLK=128 (18 strips, 1 barrier each). Grid 768 = exactly
// 3 blocks/CU, XCD-swizzled (h = blockIdx%8). P in-register (sigma trick);
// V stored PERMUTED so each V-fragment is ONE b128 read; Kt stride 42 u16
// (21 dw, odd -> 16 distinct start banks), Vs stride 138 (69 dw = 5 mod 32).
// Row-sum l via ones-MFMA. setprio(1) around MFMA clusters.
// ---------------------------------------------------------------------------
__global__ __launch_bounds__(128, 2) void attn_mfma(
    const u16* __restrict__ qkT, const u16* __restrict__ vbuf,
    u16* __restrict__ attnoT) {
  const int jb = blockIdx.x;
  const int h = jb & 7;
  const int qq = jb >> 3;
  const int it = qq % 24;
  const int b  = qq / 24;
  const int t = threadIdx.x, lane = t & 63, w = t >> 6;
  const int lo = lane & 15, g = lane >> 4;
  const int i0 = it * 96;

  const u16* qkTb = qkT + (size_t)b * NSP * 512;
  const u16* vb   = vbuf + ((size_t)b * 256 + h * 32) * NSP;
  u16* ob = attnoT + ((size_t)b * NSP + i0) * 256 + h * 32;

  __shared__ u16 Kt[2][128][42];   // [key j][d]
  __shared__ u16 Vs[2][32][138];   // [d][permuted j]

  // three Q fragments: queries i0 + w*48 + qh*16 + lo (pre-scaled by K1S)
  short8 qf[3];
#pragma unroll
  for (int qh = 0; qh < 3; ++qh)
    qf[qh] = *(const short8*)(qkTb +
              (size_t)(i0 + w * 48 + qh * 16 + lo) * 512 + h * 32 + g * 8);

  // staging (128 thr, 128-key strips):
  // K: thread t -> rows kr+32i (i=0..3), 16B at d-part kp.
  // V: thread t -> rows vr+8i (i=0..3), 16B at j-part vjp, written PERMUTED:
  //    within each 32-col block, col j=(16b1+4gg+rr) stores at 8*gg+4*b1+rr,
  //    so lane (lo,g)'s sigma fragment {4g+rr, 16+4g+rr} is contiguous 16B.
  const int kr = t >> 2, kp = (t & 3) * 8;
  const int vr = t >> 4, vjp = (t & 15) * 8;
  const int pc0 = (vjp & ~31) | (8 * ((vjp >> 2) & 3) + 4 * ((vjp >> 4) & 1));
  const u16* ksrc = qkTb + 256 + h * 32 + kp;            // + (j0+row)*512
  const u16* vsrc = vb + (size_t)vr * NSP + vjp;         // + 8i*NSP + j0

  uint4 kv[4], vv[4];
#pragma unroll
  for (int i = 0; i < 4; ++i) {
    kv[i] = *(const uint4*)(ksrc + (size_t)(kr + 32 * i) * 512);
    vv[i] = *(const uint4*)(vsrc + (size_t)(8 * i) * NSP);
  }
#pragma unroll
  for (int i = 0; i < 4; ++i) {
    *(uint4*)&Kt[0][kr + 32 * i][kp] = kv[i];
    *(uint2*)&Vs[0][vr + 8 * i][pc0]     = make_uint2(vv[i].x, vv[i].y);
    *(uint2*)&Vs[0][vr + 8 * i][pc0 + 8] = make_uint2(vv[i].z, vv[i].w);
  }
  __syncthreads();

  short8 ones;
#pragma unroll
  for (int e = 0; e < 8; ++e) ones[e] = (short)0x3F80;  // bf16 1.0

  f32x4 a0[3], a1[3], al[3];
#pragma unroll
  for (int qh = 0; qh < 3; ++qh) {
    a0[qh] = (f32x4){0, 0, 0, 0};
    a1[qh] = (f32x4){0, 0, 0, 0};
    al[qh] = (f32x4){0, 0, 0, 0};
  }

  for (int s = 0; s < 18; ++s) {
    const int cur = s & 1;
    if (s + 1 < 18) {  // prefetch next strip into regs (hidden under compute)
      const int j0n = (s + 1) * 128;
#pragma unroll
      for (int i = 0; i < 4; ++i) {
        kv[i] = *(const uint4*)(ksrc + (size_t)(j0n + kr + 32 * i) * 512);
        vv[i] = *(const uint4*)(vsrc + j0n + (size_t)(8 * i) * NSP);
      }
    }

#pragma unroll
    for (int h2 = 0; h2 < 2; ++h2) {
      // K fragments (shared by all 3 q-frags)
      short8 kf0 = *(const short8*)&Kt[cur][h2 * 64 + lo][g * 8];
      short8 kf1 = *(const short8*)&Kt[cur][h2 * 64 + 16 + lo][g * 8];
      short8 kf2 = *(const short8*)&Kt[cur][h2 * 64 + 32 + lo][g * 8];
      short8 kf3 = *(const short8*)&Kt[cur][h2 * 64 + 48 + lo][g * 8];
      // V fragments (single b128 each, permuted layout; shared by all qh)
      short8 vf00 = *(const short8*)&Vs[cur][lo][h2 * 64 + 8 * g];
      short8 vf01 = *(const short8*)&Vs[cur][lo][h2 * 64 + 32 + 8 * g];
      short8 vf10 = *(const short8*)&Vs[cur][16 + lo][h2 * 64 + 8 * g];
      short8 vf11 = *(const short8*)&Vs[cur][16 + lo][h2 * 64 + 32 + 8 * g];

#pragma unroll
      for (int qh = 0; qh < 3; ++qh) {
        __builtin_amdgcn_s_setprio(1);
        f32x4 sv0 = __builtin_amdgcn_mfma_f32_16x16x32_bf16(kf0, qf[qh], (f32x4){0,0,0,0}, 0, 0, 0);
        f32x4 sv1 = __builtin_amdgcn_mfma_f32_16x16x32_bf16(kf1, qf[qh], (f32x4){0,0,0,0}, 0, 0, 0);
        f32x4 sv2 = __builtin_amdgcn_mfma_f32_16x16x32_bf16(kf2, qf[qh], (f32x4){0,0,0,0}, 0, 0, 0);
        f32x4 sv3 = __builtin_amdgcn_mfma_f32_16x16x32_bf16(kf3, qf[qh], (f32x4){0,0,0,0}, 0, 0, 0);
        __builtin_amdgcn_s_setprio(0);

        f32x4 e0, e1, e2, e3;
#pragma unroll
        for (int r = 0; r < 4; ++r) {
          e0[r] = __builtin_amdgcn_exp2f(sv0[r]);
          e1[r] = __builtin_amdgcn_exp2f(sv1[r]);
          e2[r] = __builtin_amdgcn_exp2f(sv2[r]);
          e3[r] = __builtin_amdgcn_exp2f(sv3[r]);
        }
        uint4 P0 = {cvtpk(e0[0], e0[1]), cvtpk(e0[2], e0[3]),
                    cvtpk(e1[0], e1[1]), cvtpk(e1[2], e1[3])};
        uint4 P1 = {cvtpk(e2[0], e2[1]), cvtpk(e2[2], e2[3]),
                    cvtpk(e3[0], e3[1]), cvtpk(e3[2], e3[3])};
        short8 pf0 = __builtin_bit_cast(short8, P0);
        short8 pf1 = __builtin_bit_cast(short8, P1);

        __builtin_amdgcn_s_setprio(1);
        a0[qh] = __builtin_amdgcn_mfma_f32_16x16x32_bf16(pf0, vf00, a0[qh], 0, 0, 0);
        a1[qh] = __builtin_amdgcn_mfma_f32_16x16x32_bf16(pf0, vf10, a1[qh], 0, 0, 0);
        al[qh] = __builtin_amdgcn_mfma_f32_16x16x32_bf16(pf0, ones, al[qh], 0, 0, 0);
        a0[qh] = __builtin_amdgcn_mfma_f32_16x16x32_bf16(pf1, vf01, a0[qh], 0, 0, 0);
        a1[qh] = __builtin_amdgcn_mfma_f32_16x16x32_bf16(pf1, vf11, a1[qh], 0, 0, 0);
        al[qh] = __builtin_amdgcn_mfma_f32_16x16x32_bf16(pf1, ones, al[qh], 0, 0, 0);
        __builtin_amdgcn_s_setprio(0);
      }
    }

    if (s + 1 < 18) {  // write next strip into the other buffer
#pragma unroll
      for (int i = 0; i < 4; ++i) {
        *(uint4*)&Kt[cur ^ 1][kr + 32 * i][kp] = kv[i];
        *(uint2*)&Vs[cur ^ 1][vr + 8 * i][pc0]     = make_uint2(vv[i].x, vv[i].y);
        *(uint2*)&Vs[cur ^ 1][vr + 8 * i][pc0 + 8] = make_uint2(vv[i].z, vv[i].w);
      }
    }
    __syncthreads();
  }

  // ---- normalize + bf16 store to attnoT[n][c] ----
#pragma unroll
  for (int qh = 0; qh < 3; ++qh)
#pragma unroll
    for (int r = 0; r < 4; ++r) {
      float inv = 1.0f / al[qh][r];
      int row = w * 48 + qh * 16 + g * 4 + r;
      ob[(size_t)row * 256 + lo]      = f2bf(a0[qh][r] * inv);
      ob[(size_t)row * 256 + 16 + lo] = f2bf(a1[qh][r] * inv);
    }
}

// ---------------------------------------------------------------------------
extern "C" void kernel_launch(void* const* d_in, const int* in_sizes, int n_in,
                              void* d_out, int out_size, void* d_ws, size_t ws_size,
                              hipStream_t stream) {
  const float* x     = (const float*)d_in[0];  // [4][256][48][48]
  const float* w_qkv = (const float*)d_in[1];  // [768][256]
  const float* w_out = (const float*)d_in[2];  // [256][256]
  const float* b_out = (const float*)d_in[3];  // [256]
  float* out = (float*)d_out;                  // [4][256][2304]

  u16* wbf    = (u16*)d_ws;                    // wqkv 196608 then wout 65536
  u16* xT     = wbf + 262144;                  // [4][2304][256]
  u16* qkT    = xT + (size_t)NB * NSP * 256;   // [4][2304][512]
  u16* vbuf   = qkT + (size_t)NB * NSP * 512;  // [4][256][2304]
  u16* attnoT = vbuf + (size_t)NB * 256 * NSP; // [4][2304][256]

  dim3 blk(256);
  convert_w<<<256, blk, 0, stream>>>(w_qkv, w_out, wbf);
  transpose_x<<<dim3(NSP / 32, 8, NB), blk, 0, stream>>>(x, xT);
  gemm_mfma<0><<<dim3(NSP / 64, 12, NB), blk, 0, stream>>>(
      wbf, xT, qkT, vbuf, nullptr, nullptr, NSP);
  attn_mfma<<<dim3(768), dim3(128), 0, stream>>>(qkT, vbuf, attnoT);
  gemm_mfma<1><<<dim3(NSP / 64, 4, NB), blk, 0, stream>>>(
      wbf + 196608, attnoT, nullptr, nullptr, out, b_out, NSP);
}